// Round 12
// baseline (381.677 us; speedup 1.0000x reference)
//
#include <hip/hip_runtime.h>
#include <hip/hip_bf16.h>

using bf16x8 = __attribute__((ext_vector_type(8))) short;
using f32x4  = __attribute__((ext_vector_type(4))) float;

// ---------- dtype-dispatched load helpers ----------
__device__ __forceinline__ float ldf(const void* p, size_t i, float isf){
  if (isf > 0.5f) return ((const float*)p)[i];
  unsigned int u = ((unsigned int)((const unsigned short*)p)[i]) << 16;
  return __uint_as_float(u);
}
__device__ __forceinline__ unsigned short f2bf(float v){
  unsigned int u = __float_as_uint(v);
  u = (u + 0x7FFFu + ((u >> 16) & 1u)) >> 16;   // RNE
  return (unsigned short)u;
}
__device__ __forceinline__ unsigned int pk2(float a, float b){
  return (unsigned int)f2bf(a) | ((unsigned int)f2bf(b) << 16);
}
__device__ __forceinline__ float lo16(unsigned int u){ return __uint_as_float(u << 16); }
__device__ __forceinline__ float hi16(unsigned int u){ return __uint_as_float(u & 0xFFFF0000u); }

// ---------- diagnostics ----------
__global__ void k_fill(unsigned short* o, unsigned short v, int n){
  int i = blockIdx.x*blockDim.x + threadIdx.x;
  if (i < n) o[i] = v;
}

// ---------- fused: dtype detect + weight convert (block 0) + zero cnt/st (blocks >0) ----------
__global__ void k_prep(const unsigned short* xh, const unsigned int* eu,
                       float* flag, int nelemX, long long E,
                       const void* W1, const void* W2, const void* W3, const void* W4,
                       unsigned short* __restrict__ Wt1, unsigned short* __restrict__ Wt2,
                       unsigned short* __restrict__ Wt3, float* __restrict__ W4f,
                       int* __restrict__ cnt, float* __restrict__ stAll, int n){
  int t = threadIdx.x;
  if (blockIdx.x > 0){
    int total = n + 4608;                 // cnt[N] + 3 layers x 8 reps x 192 stats
    for (int i = (int)(blockIdx.x-1)*256 + t; i < total; i += (int)(gridDim.x-1)*256){
      if (i < n) cnt[i] = 0; else stAll[i - n] = 0.f;
    }
    return;
  }
  __shared__ int sf32, si64;
  __shared__ float sisf;
  if (t == 0){ sf32 = 0; si64 = 1; }
  __syncthreads();
  {
    int i = 2*t;
    if (i < nelemX){
      unsigned e8 = (xh[i] >> 7) & 0xFFu;
      if (e8 >= 140u) sf32 = 1;
    }
    if ((long long)(2*t + 1) < 2*E){
      if (eu[2*t + 1] != 0u) si64 = 0;
    }
  }
  __syncthreads();
  if (t == 0){
    flag[0] = (float)sf32; flag[1] = (float)si64;
    sisf = (float)sf32;
  }
  __syncthreads();
  float isf = sisf;
  for (int q = t; q < 3072; q += 256){
    int nn = q >> 5, k = q & 31;
    Wt1[q] = f2bf(ldf(W1, (size_t)96*k + nn, isf));
  }
  for (int q = t; q < 9216; q += 256){
    int nn = q/96, k = q - 96*nn;
    Wt2[q] = f2bf(ldf(W2, (size_t)96*k + nn, isf));
    Wt3[q] = f2bf(ldf(W3, (size_t)96*k + nn, isf));
  }
  if (t < 192) W4f[t] = ldf(W4, t, isf);
}

// ---------- degree count ----------
__global__ void k_cnt(const int* __restrict__ ei, const float* __restrict__ flag,
                      int* __restrict__ cnt, long long E, int n){
  long long i = (long long)blockIdx.x*blockDim.x + threadIdx.x;
  if (i >= E) return;
  int d = (flag[1] > 0.5f) ? ei[2*E + 2*i] : ei[E + i];
  if ((unsigned)d < (unsigned)n) atomicAdd(&cnt[d], 1);
}

// ---------- single-block exclusive scan: rowst, cursor, dinv (1024 threads) ----------
__global__ void k_scan(const int* __restrict__ cnt, int* __restrict__ rowst,
                       int* __restrict__ cursor, float* __restrict__ dinv, int n){
  __shared__ int woff[16];
  __shared__ int chtot;
  __shared__ int carry_s;
  int tid = threadIdx.x;
  int lane = tid & 63, wid = tid >> 6;
  if (tid == 0) carry_s = 0;
  __syncthreads();
  for (int base = 0; base < n; base += 1024){
    int i = base + tid;
    int v = (i < n) ? cnt[i] : 0;
    int s = v;
    #pragma unroll
    for (int off = 1; off < 64; off <<= 1){
      int u = __shfl_up(s, off, 64);
      if (lane >= off) s += u;
    }
    if (lane == 63) woff[wid] = s;
    __syncthreads();
    if (tid < 16){
      int w = woff[tid];
      int ws_ = w;
      #pragma unroll
      for (int off = 1; off < 16; off <<= 1){
        int u = __shfl_up(ws_, off, 64);
        if (tid >= off) ws_ += u;
      }
      woff[tid] = ws_ - w;            // exclusive wave offset
      if (tid == 15) chtot = ws_;     // chunk total
    }
    __syncthreads();
    int carry = carry_s;
    if (i < n){
      int r = carry + woff[wid] + s - v;
      rowst[i] = r;
      cursor[i] = r;
      dinv[i]  = rsqrtf((float)(1 + v));
    }
    __syncthreads();
    if (tid == 0) carry_s = carry + chtot;
  }
  __syncthreads();
  if (tid == 0) rowst[n] = carry_s;
}

// ---------- merged: XCD-partitioned slot fill (blocks < gF8) + MFMA layer 1 (rest) ----------
#define FS_CHUNK 4096
template<typename IT>
__global__ __launch_bounds__(256) void k_fl1(const int* __restrict__ ei,
      const float* __restrict__ flag, int* __restrict__ cursor, IT* __restrict__ csr,
      long long E, int n, int gF8,
      const void* __restrict__ x, const unsigned short* __restrict__ Wt1b,
      const float* __restrict__ dinv, unsigned short* __restrict__ HS){
  __shared__ __align__(16) unsigned short Xs[64][40];
  __shared__ __align__(16) unsigned short Wt[96][40];
  int t = threadIdx.x;
  if ((int)blockIdx.x < gF8){
    // ---- CSR slot fill, dst-partitioned per XCD ----
    int part = blockIdx.x & 7;
    long long base = (long long)(blockIdx.x >> 3) * FS_CHUNK;
    int pl = (int)(((long long)n *  part     ) >> 3);
    int pr = (int)(((long long)n * (part + 1)) >> 3);
    bool i64 = (flag[1] > 0.5f);
    long long lim = base + FS_CHUNK < E ? base + FS_CHUNK : E;
    for (long long i = base + t; i < lim; i += 256){
      int s, d;
      if (i64){ s = ei[2*i]; d = ei[2*E + 2*i]; }
      else    { s = ei[i];   d = ei[E + i];     }
      if (d >= pl && d < pr && (unsigned)s < (unsigned)n){
        int p = atomicAdd(&cursor[d], 1);
        csr[p] = (IT)s;
      }
    }
    return;
  }
  // ---- MFMA layer 1 ----
  int bid = blockIdx.x - gF8;
  float isf = flag[0];
  for (int q = t; q < 384; q += 256){
    uint4 v = ((const uint4*)Wt1b)[q];
    *(uint4*)&Wt[q >> 2][(q & 3)*8] = v;
  }
  {
    int row = t >> 2, part = t & 3;
    int node = bid*64 + row;
    uint4 o;
    if (node < n){
      if (isf > 0.5f){
        const float* xr = (const float*)x + (size_t)32*node + 8*part;
        o.x = pk2(xr[0], xr[1]); o.y = pk2(xr[2], xr[3]);
        o.z = pk2(xr[4], xr[5]); o.w = pk2(xr[6], xr[7]);
      } else {
        o = ((const uint4*)x)[(size_t)4*node + part];
      }
    } else { o.x = o.y = o.z = o.w = 0u; }
    *(uint4*)&Xs[row][8*part] = o;
  }
  __syncthreads();

  int wv = t >> 6, lane = t & 63;
  int m = lane & 15, quad = lane >> 4;
  bf16x8 av = *(const bf16x8*)&Xs[16*wv + m][8*quad];
  f32x4 acc[6];
  #pragma unroll
  for (int c = 0; c < 6; ++c) acc[c] = (f32x4)(0.f);
  #pragma unroll
  for (int c = 0; c < 6; ++c){
    bf16x8 bv = *(const bf16x8*)&Wt[16*c + m][8*quad];
    acc[c] = __builtin_amdgcn_mfma_f32_16x16x32_bf16(av, bv, acc[c], 0, 0, 0);
  }
  int rowbase = bid*64 + 16*wv + 4*quad;
  float div[4];
  #pragma unroll
  for (int r = 0; r < 4; ++r){ int rr = rowbase + r; div[r] = (rr < n) ? dinv[rr] : 0.f; }
  #pragma unroll
  for (int c = 0; c < 6; ++c){
    int col = 16*c + m;
    #pragma unroll
    for (int r = 0; r < 4; ++r){
      int rr = rowbase + r;
      if (rr < n) HS[(size_t)96*rr + col] = f2bf(acc[c][r]*div[r]);
    }
  }
}

// ---------- CSR gather aggregation (bf16) + fused BN stats into 8-replica banks ----------
#define ACC8(v) { a0+=lo16((v).x); a1+=hi16((v).x); a2+=lo16((v).y); a3+=hi16((v).y); \
                  a4+=lo16((v).z); a5+=hi16((v).z); a6+=lo16((v).w); a7+=hi16((v).w); }
template<typename IT>
__global__ __launch_bounds__(192) void k_agg(const uint4* __restrict__ hsr,
      const int* __restrict__ rowst, const IT* __restrict__ csr,
      const float* __restrict__ dinv, uint4* __restrict__ zb4,
      float* __restrict__ stout, int n){
  __shared__ float ls[16][97], lq[16][97];   // pad 97: spreads banks
  int g = threadIdx.x, ty = threadIdx.y;
  int t = ty*12 + g;
  int node = blockIdx.x*16 + ty;
  float r[8];
  if (node < n){
    uint4 v = hsr[(size_t)node*12 + g];            // self-loop term
    float a0 = lo16(v.x), a1 = hi16(v.x), a2 = lo16(v.y), a3 = hi16(v.y);
    float a4 = lo16(v.z), a5 = hi16(v.z), a6 = lo16(v.w), a7 = hi16(v.w);
    int b = rowst[node], e = rowst[node+1];
    int j = b;
    for (; j + 7 < e; j += 8){
      uint4 v0 = hsr[(size_t)csr[j]  *12 + g];
      uint4 v1 = hsr[(size_t)csr[j+1]*12 + g];
      uint4 v2 = hsr[(size_t)csr[j+2]*12 + g];
      uint4 v3 = hsr[(size_t)csr[j+3]*12 + g];
      uint4 v4 = hsr[(size_t)csr[j+4]*12 + g];
      uint4 v5 = hsr[(size_t)csr[j+5]*12 + g];
      uint4 v6 = hsr[(size_t)csr[j+6]*12 + g];
      uint4 v7 = hsr[(size_t)csr[j+7]*12 + g];
      ACC8(v0); ACC8(v1); ACC8(v2); ACC8(v3);
      ACC8(v4); ACC8(v5); ACC8(v6); ACC8(v7);
    }
    for (; j + 3 < e; j += 4){
      uint4 v0 = hsr[(size_t)csr[j]  *12 + g];
      uint4 v1 = hsr[(size_t)csr[j+1]*12 + g];
      uint4 v2 = hsr[(size_t)csr[j+2]*12 + g];
      uint4 v3 = hsr[(size_t)csr[j+3]*12 + g];
      ACC8(v0); ACC8(v1); ACC8(v2); ACC8(v3);
    }
    for (; j < e; ++j){
      uint4 vv = hsr[(size_t)csr[j]*12 + g];
      ACC8(vv);
    }
    float di = dinv[node];
    uint4 o;
    o.x = pk2(a0*di, a1*di);
    o.y = pk2(a2*di, a3*di);
    o.z = pk2(a4*di, a5*di);
    o.w = pk2(a6*di, a7*di);
    zb4[(size_t)node*12 + g] = o;
    // stats on the rounded values the next layer will consume:
    r[0]=lo16(o.x); r[1]=hi16(o.x); r[2]=lo16(o.y); r[3]=hi16(o.y);
    r[4]=lo16(o.z); r[5]=hi16(o.z); r[6]=lo16(o.w); r[7]=hi16(o.w);
  } else {
    #pragma unroll
    for (int jj = 0; jj < 8; ++jj) r[jj] = 0.f;
  }
  #pragma unroll
  for (int jj = 0; jj < 8; ++jj){
    ls[ty][8*g + jj] = r[jj];
    lq[ty][8*g + jj] = r[jj]*r[jj];
  }
  __syncthreads();
  if (t < 96){
    float s = 0.f, q = 0.f;
    #pragma unroll
    for (int rr = 0; rr < 16; ++rr){ s += ls[rr][t]; q += lq[rr][t]; }
    int rep = blockIdx.x & 7;
    atomicAdd(&stout[192*rep + t],      s);
    atomicAdd(&stout[192*rep + 96 + t], q);
  }
}

// ---------- MFMA mid layer: HS = dinv * (relu(BN(Zb)) @ W); st = 8-replica sums ----------
__global__ __launch_bounds__(256) void k_linm(const unsigned short* __restrict__ zb,
      const unsigned short* __restrict__ Wtb, const float* __restrict__ st,
      const void* __restrict__ gam, const void* __restrict__ bet,
      const float* __restrict__ flag, const float* __restrict__ dinv,
      unsigned short* __restrict__ HS, int n, float invN){
  __shared__ float sa[96], sc[96];
  __shared__ __align__(16) unsigned short Ys[64][104];
  __shared__ __align__(16) unsigned short Wt[96][104];
  int t = threadIdx.x;
  if (t < 96){
    float ssum = 0.f, qsum = 0.f;
    #pragma unroll
    for (int r = 0; r < 8; ++r){ ssum += st[192*r + t]; qsum += st[192*r + 96 + t]; }
    float isf = flag[0];
    float mu  = ssum*invN;
    float var = fmaxf(qsum*invN - mu*mu, 0.f);
    float istd = rsqrtf(var + 1e-5f);
    float a = ldf(gam, t, isf)*istd;
    sa[t] = a; sc[t] = ldf(bet, t, isf) - mu*a;
  }
  for (int q = t; q < 1152; q += 256){
    uint4 v = ((const uint4*)Wtb)[q];
    *(uint4*)&Wt[q/12][8*(q - 12*(q/12))] = v;
  }
  __syncthreads();
  {
    int row = t >> 2, part = t & 3;
    int node = blockIdx.x*64 + row;
    if (node < n){
      const uint4* zr = (const uint4*)(zb + (size_t)96*node) + 3*part;
      #pragma unroll
      for (int q = 0; q < 3; ++q){
        uint4 zz = zr[q];
        int k = 24*part + 8*q;
        float y0 = fmaxf(lo16(zz.x)*sa[k]   + sc[k],   0.f);
        float y1 = fmaxf(hi16(zz.x)*sa[k+1] + sc[k+1], 0.f);
        float y2 = fmaxf(lo16(zz.y)*sa[k+2] + sc[k+2], 0.f);
        float y3 = fmaxf(hi16(zz.y)*sa[k+3] + sc[k+3], 0.f);
        float y4 = fmaxf(lo16(zz.z)*sa[k+4] + sc[k+4], 0.f);
        float y5 = fmaxf(hi16(zz.z)*sa[k+5] + sc[k+5], 0.f);
        float y6 = fmaxf(lo16(zz.w)*sa[k+6] + sc[k+6], 0.f);
        float y7 = fmaxf(hi16(zz.w)*sa[k+7] + sc[k+7], 0.f);
        *(unsigned int*)&Ys[row][k]     = pk2(y0, y1);
        *(unsigned int*)&Ys[row][k + 2] = pk2(y2, y3);
        *(unsigned int*)&Ys[row][k + 4] = pk2(y4, y5);
        *(unsigned int*)&Ys[row][k + 6] = pk2(y6, y7);
      }
    } else {
      unsigned int* yp = (unsigned int*)&Ys[row][24*part];
      #pragma unroll
      for (int q = 0; q < 12; ++q) yp[q] = 0u;
    }
  }
  __syncthreads();

  int wv = t >> 6, lane = t & 63;
  int m = lane & 15, quad = lane >> 4;
  bf16x8 av[3];
  #pragma unroll
  for (int kt = 0; kt < 3; ++kt)
    av[kt] = *(const bf16x8*)&Ys[16*wv + m][32*kt + 8*quad];
  f32x4 acc[6];
  #pragma unroll
  for (int c = 0; c < 6; ++c) acc[c] = (f32x4)(0.f);
  #pragma unroll
  for (int c = 0; c < 6; ++c){
    const unsigned short* wrow = &Wt[16*c + m][8*quad];
    #pragma unroll
    for (int kt = 0; kt < 3; ++kt){
      bf16x8 bv = *(const bf16x8*)(wrow + 32*kt);
      acc[c] = __builtin_amdgcn_mfma_f32_16x16x32_bf16(av[kt], bv, acc[c], 0, 0, 0);
    }
  }
  int rowbase = blockIdx.x*64 + 16*wv + 4*quad;
  float div[4];
  #pragma unroll
  for (int r = 0; r < 4; ++r){ int rr = rowbase + r; div[r] = (rr < n) ? dinv[rr] : 0.f; }
  #pragma unroll
  for (int c = 0; c < 6; ++c){
    int col = 16*c + m;
    #pragma unroll
    for (int r = 0; r < 4; ++r){
      int rr = rowbase + r;
      if (rr < n) HS[(size_t)96*rr + col] = f2bf(acc[c][r]*div[r]);
    }
  }
}

// ---------- layer 4 (96->2, VALU); st = 8-replica sums ----------
__global__ __launch_bounds__(256) void k_lin4(const unsigned short* __restrict__ zb,
      const float* __restrict__ Wf, const float* __restrict__ st,
      const void* __restrict__ gam, const void* __restrict__ bet,
      const float* __restrict__ flag, const float* __restrict__ dinv,
      float* __restrict__ hs2, int n, float invN){
  __shared__ float sa[96], sc[96];
  int t = threadIdx.x;
  if (t < 96){
    float ssum = 0.f, qsum = 0.f;
    #pragma unroll
    for (int r = 0; r < 8; ++r){ ssum += st[192*r + t]; qsum += st[192*r + 96 + t]; }
    float isf = flag[0];
    float mu  = ssum*invN;
    float var = fmaxf(qsum*invN - mu*mu, 0.f);
    float istd = rsqrtf(var + 1e-5f);
    float a = ldf(gam, t, isf)*istd;
    sa[t] = a; sc[t] = ldf(bet, t, isf) - mu*a;
  }
  __syncthreads();
  int i = blockIdx.x*blockDim.x + t;
  if (i >= n) return;
  const uint4* zr = (const uint4*)(zb + (size_t)96*i);
  float a0 = 0.f, a1 = 0.f;
  #pragma unroll
  for (int q = 0; q < 12; ++q){
    uint4 zz = zr[q];
    int k = 8*q;
    float y;
    y = fmaxf(lo16(zz.x)*sa[k]   + sc[k],   0.f); a0 += y*Wf[2*k];    a1 += y*Wf[2*k+1];
    y = fmaxf(hi16(zz.x)*sa[k+1] + sc[k+1], 0.f); a0 += y*Wf[2*k+2];  a1 += y*Wf[2*k+3];
    y = fmaxf(lo16(zz.y)*sa[k+2] + sc[k+2], 0.f); a0 += y*Wf[2*k+4];  a1 += y*Wf[2*k+5];
    y = fmaxf(hi16(zz.y)*sa[k+3] + sc[k+3], 0.f); a0 += y*Wf[2*k+6];  a1 += y*Wf[2*k+7];
    y = fmaxf(lo16(zz.z)*sa[k+4] + sc[k+4], 0.f); a0 += y*Wf[2*k+8];  a1 += y*Wf[2*k+9];
    y = fmaxf(hi16(zz.z)*sa[k+5] + sc[k+5], 0.f); a0 += y*Wf[2*k+10]; a1 += y*Wf[2*k+11];
    y = fmaxf(lo16(zz.w)*sa[k+6] + sc[k+6], 0.f); a0 += y*Wf[2*k+12]; a1 += y*Wf[2*k+13];
    y = fmaxf(hi16(zz.w)*sa[k+7] + sc[k+7], 0.f); a0 += y*Wf[2*k+14]; a1 += y*Wf[2*k+15];
  }
  float di = dinv[i];
  hs2[(size_t)2*i]   = di*a0;
  hs2[(size_t)2*i+1] = di*a1;
}

template<typename IT>
__global__ void k_agg2(const float2* __restrict__ hs2, const int* __restrict__ rowst,
                       const IT* __restrict__ csr, const float* __restrict__ dinv,
                       const void* __restrict__ b4, const float* __restrict__ flag,
                       void* __restrict__ out, int n){
  int node = blockIdx.x*blockDim.x + threadIdx.x;
  if (node >= n) return;
  float2 a = hs2[node];
  int b = rowst[node], e = rowst[node+1];
  for (int j = b; j < e; ++j){
    float2 v = hs2[(size_t)csr[j]];
    a.x += v.x; a.y += v.y;
  }
  float isf = flag[0];
  float di = dinv[node];
  float v0 = a.x*di + ldf(b4, 0, isf);
  float v1 = a.y*di + ldf(b4, 1, isf);
  if (isf > 0.5f){
    ((float*)out)[(size_t)2*node]   = v0;
    ((float*)out)[(size_t)2*node+1] = v1;
  } else {
    ((unsigned short*)out)[(size_t)2*node]   = f2bf(v0);
    ((unsigned short*)out)[(size_t)2*node+1] = f2bf(v1);
  }
}

extern "C" void kernel_launch(void* const* d_in, const int* in_sizes, int n_in,
                              void* d_out, int out_size, void* d_ws, size_t ws_size,
                              hipStream_t stream)
{
  const int B = 256;
  unsigned short* outh = (unsigned short*)d_out;

  if (n_in < 16){
    k_fill<<<(out_size+B-1)/B, B, 0, stream>>>(outh, 0x3F40u, out_size); return;
  }
  const int N = in_sizes[0] / 32;
  const long long E = in_sizes[1] / 2;
  if (in_sizes[0] % 32 != 0 || out_size != 2*N){
    k_fill<<<(out_size+B-1)/B, B, 0, stream>>>(outh, 0x3F60u, out_size); return;
  }
  const bool u16 = (N < 65536);

  // ---- workspace layout ----
  size_t Npad = ((size_t)N + 3) & ~(size_t)3;
  float* ws   = (float*)d_ws;
  float* dinv = ws;                               // Npad
  float* hs2  = dinv + Npad;                      // 2N
  float* flag = hs2 + (size_t)2*N;                // 4
  float* stAll= flag + 4;                         // 4608 = 3 layers x 8 reps x 192
  float* W4f  = stAll + 4608;                     // 192
  unsigned short* Wt1b = (unsigned short*)(W4f + 192);   // 3072 bf16
  unsigned short* Wt2b = Wt1b + 3072;             // 9216
  unsigned short* Wt3b = Wt2b + 9216;             // 9216
  int* cnt    = (int*)(Wt3b + 9216);              // N
  int* cursor = cnt + N;                          // N
  int* rowst  = cursor + N;                       // N+1
  void* csrv  = (void*)(rowst + N + 1);           // E entries (u16 or int)
  size_t csrBytes = (size_t)E * (u16 ? 2 : 4);
  uintptr_t hp_ = (uintptr_t)csrv + csrBytes;
  hp_ = (hp_ + 15) & ~(uintptr_t)15;
  unsigned short* HS = (unsigned short*)hp_;      // 96N bf16
  unsigned short* Zb = HS + (size_t)96*N;         // 96N bf16

  size_t needB = ((uintptr_t)(Zb + (size_t)96*N) - (uintptr_t)d_ws) + 64;
  if (ws_size < needB){
    k_fill<<<(out_size+B-1)/B, B, 0, stream>>>(outh, 0x3F00u, out_size); return;
  }

  const void* x  = d_in[0];
  const int*  ei = (const int*)d_in[1];
  const void* W1 = d_in[2];
  const void* g1 = d_in[4];  const void* be1 = d_in[5];
  const void* W2 = d_in[6];
  const void* g2 = d_in[8];  const void* be2 = d_in[9];
  const void* W3 = d_in[10];
  const void* g3 = d_in[12]; const void* be3 = d_in[13];
  const void* W4 = d_in[14];
  const void* b4 = d_in[15];

  float* stA = stAll;
  float* stB = stAll + 1536;
  float* stC = stAll + 3072;

  int gN  = (N + B - 1)/B;
  int gE  = (int)((E + B - 1)/B);
  int gA  = (N + 15)/16;
  int gL  = (N + 63)/64;
  int gF8 = (int)((E + FS_CHUNK - 1)/FS_CHUNK) * 8;
  float invN = 1.0f / (float)N;
  dim3 ablk(12,16);

  // 1) detect + weights + zero cnt/st
  k_prep<<<33, B, 0, stream>>>((const unsigned short*)x, (const unsigned int*)ei,
                               flag, in_sizes[0], E, W1, W2, W3, W4,
                               Wt1b, Wt2b, Wt3b, W4f, cnt, stAll, N);
  // 2) degree count
  k_cnt<<<gE, B, 0, stream>>>(ei, flag, cnt, E, N);
  // 3) scan -> rowst, cursor, dinv
  k_scan<<<1, 1024, 0, stream>>>(cnt, rowst, cursor, dinv, N);

  if (u16){
    unsigned short* csr = (unsigned short*)csrv;
    // 4) CSR fill + MFMA layer 1 (merged, overlap)
    k_fl1<unsigned short><<<gF8 + gL, B, 0, stream>>>(ei, flag, cursor, csr, E, N, gF8,
                                                      x, Wt1b, dinv, HS);
    // 5..9) layers 1..3 agg(+stats) / linm
    k_agg<unsigned short><<<gA, ablk, 0, stream>>>((const uint4*)HS, rowst, csr, dinv, (uint4*)Zb, stA, N);
    k_linm<<<gL, B, 0, stream>>>(Zb, Wt2b, stA, g1, be1, flag, dinv, HS, N, invN);
    k_agg<unsigned short><<<gA, ablk, 0, stream>>>((const uint4*)HS, rowst, csr, dinv, (uint4*)Zb, stB, N);
    k_linm<<<gL, B, 0, stream>>>(Zb, Wt3b, stB, g2, be2, flag, dinv, HS, N, invN);
    k_agg<unsigned short><<<gA, ablk, 0, stream>>>((const uint4*)HS, rowst, csr, dinv, (uint4*)Zb, stC, N);
    // 10..11) layer 4 + output
    k_lin4<<<gN, B, 0, stream>>>(Zb, W4f, stC, g3, be3, flag, dinv, hs2, N, invN);
    k_agg2<unsigned short><<<gN, B, 0, stream>>>((const float2*)hs2, rowst, csr, dinv, b4, flag, d_out, N);
  } else {
    int* csr = (int*)csrv;
    k_fl1<int><<<gF8 + gL, B, 0, stream>>>(ei, flag, cursor, csr, E, N, gF8,
                                           x, Wt1b, dinv, HS);
    k_agg<int><<<gA, ablk, 0, stream>>>((const uint4*)HS, rowst, csr, dinv, (uint4*)Zb, stA, N);
    k_linm<<<gL, B, 0, stream>>>(Zb, Wt2b, stA, g1, be1, flag, dinv, HS, N, invN);
    k_agg<int><<<gA, ablk, 0, stream>>>((const uint4*)HS, rowst, csr, dinv, (uint4*)Zb, stB, N);
    k_linm<<<gL, B, 0, stream>>>(Zb, Wt3b, stB, g2, be2, flag, dinv, HS, N, invN);
    k_agg<int><<<gA, ablk, 0, stream>>>((const uint4*)HS, rowst, csr, dinv, (uint4*)Zb, stC, N);
    k_lin4<<<gN, B, 0, stream>>>(Zb, W4f, stC, g3, be3, flag, dinv, hs2, N, invN);
    k_agg2<int><<<gN, B, 0, stream>>>((const float2*)hs2, rowst, csr, dinv, b4, flag, d_out, N);
  }
}

// Round 13
// 340.810 us; speedup vs baseline: 1.1199x; 1.1199x over previous
//
#include <hip/hip_runtime.h>
#include <hip/hip_bf16.h>

using bf16x8 = __attribute__((ext_vector_type(8))) short;
using f32x4  = __attribute__((ext_vector_type(4))) float;

// ---------- dtype-dispatched load helpers ----------
__device__ __forceinline__ float ldf(const void* p, size_t i, float isf){
  if (isf > 0.5f) return ((const float*)p)[i];
  unsigned int u = ((unsigned int)((const unsigned short*)p)[i]) << 16;
  return __uint_as_float(u);
}
__device__ __forceinline__ unsigned short f2bf(float v){
  unsigned int u = __float_as_uint(v);
  u = (u + 0x7FFFu + ((u >> 16) & 1u)) >> 16;   // RNE
  return (unsigned short)u;
}
__device__ __forceinline__ unsigned int pk2(float a, float b){
  return (unsigned int)f2bf(a) | ((unsigned int)f2bf(b) << 16);
}
__device__ __forceinline__ float lo16(unsigned int u){ return __uint_as_float(u << 16); }
__device__ __forceinline__ float hi16(unsigned int u){ return __uint_as_float(u & 0xFFFF0000u); }

// ---------- diagnostics ----------
__global__ void k_fill(unsigned short* o, unsigned short v, int n){
  int i = blockIdx.x*blockDim.x + threadIdx.x;
  if (i < n) o[i] = v;
}

// ---------- fused: dtype detect + weight convert (block 0) + zero cnt/st/gctr (blocks >0) ----------
__global__ void k_prep(const unsigned short* xh, const unsigned int* eu,
                       float* flag, int nelemX, long long E,
                       const void* W1, const void* W2, const void* W3, const void* W4,
                       unsigned short* __restrict__ Wt1, unsigned short* __restrict__ Wt2,
                       unsigned short* __restrict__ Wt3, float* __restrict__ W4f,
                       int* __restrict__ cnt, float* __restrict__ stAll, int n){
  int t = threadIdx.x;
  if (blockIdx.x > 0){
    int total = n + 4609;                 // cnt[N] + 3x8x192 stats + gctr
    for (int i = (int)(blockIdx.x-1)*256 + t; i < total; i += (int)(gridDim.x-1)*256){
      if (i < n) cnt[i] = 0; else stAll[i - n] = 0.f;   // 0.0f bits == int 0
    }
    return;
  }
  __shared__ int sf32, si64;
  __shared__ float sisf;
  if (t == 0){ sf32 = 0; si64 = 1; }
  __syncthreads();
  {
    int i = 2*t;
    if (i < nelemX){
      unsigned e8 = (xh[i] >> 7) & 0xFFu;
      if (e8 >= 140u) sf32 = 1;
    }
    if ((long long)(2*t + 1) < 2*E){
      if (eu[2*t + 1] != 0u) si64 = 0;
    }
  }
  __syncthreads();
  if (t == 0){
    flag[0] = (float)sf32; flag[1] = (float)si64;
    sisf = (float)sf32;
  }
  __syncthreads();
  float isf = sisf;
  for (int q = t; q < 3072; q += 256){
    int nn = q >> 5, k = q & 31;
    Wt1[q] = f2bf(ldf(W1, (size_t)96*k + nn, isf));
  }
  for (int q = t; q < 9216; q += 256){
    int nn = q/96, k = q - 96*nn;
    Wt2[q] = f2bf(ldf(W2, (size_t)96*k + nn, isf));
    Wt3[q] = f2bf(ldf(W3, (size_t)96*k + nn, isf));
  }
  if (t < 192) W4f[t] = ldf(W4, t, isf);
}

// ---------- degree count ----------
__global__ void k_cnt(const int* __restrict__ ei, const float* __restrict__ flag,
                      int* __restrict__ cnt, long long E, int n){
  long long i = (long long)blockIdx.x*blockDim.x + threadIdx.x;
  if (i >= E) return;
  int d = (flag[1] > 0.5f) ? ei[2*E + 2*i] : ei[E + i];
  if ((unsigned)d < (unsigned)n) atomicAdd(&cnt[d], 1);
}

// ---------- unordered row allocation: wave prefix + one atomicAdd per wave ----------
// Rows get disjoint (arbitrary-order) csr ranges; length lives in cnt[].
__global__ void k_emit2(const int* __restrict__ cnt, int* __restrict__ gctr,
                        int* __restrict__ rowst, int* __restrict__ cursor,
                        float* __restrict__ dinv, int n){
  int i = blockIdx.x*256 + threadIdx.x;
  int lane = threadIdx.x & 63;
  int v = (i < n) ? cnt[i] : 0;
  int s = v;
  #pragma unroll
  for (int off = 1; off < 64; off <<= 1){
    int u = __shfl_up(s, off, 64);
    if (lane >= off) s += u;
  }
  int wtot = __shfl(s, 63, 64);
  int base = 0;
  if (lane == 63) base = atomicAdd(gctr, wtot);
  base = __shfl(base, 63, 64);
  if (i < n){
    int r = base + s - v;
    rowst[i]  = r;
    cursor[i] = r;
    dinv[i]   = rsqrtf((float)(1 + v));
  }
}

// ---------- merged: XCD-partitioned slot fill (blocks < gF8) + MFMA layer 1 (rest) ----------
#define FS_CHUNK 4096
template<typename IT>
__global__ __launch_bounds__(256) void k_fl1(const int* __restrict__ ei,
      const float* __restrict__ flag, int* __restrict__ cursor, IT* __restrict__ csr,
      long long E, int n, int gF8,
      const void* __restrict__ x, const unsigned short* __restrict__ Wt1b,
      const float* __restrict__ dinv, unsigned short* __restrict__ HS){
  __shared__ __align__(16) unsigned short Xs[64][40];
  __shared__ __align__(16) unsigned short Wt[96][40];
  int t = threadIdx.x;
  if ((int)blockIdx.x < gF8){
    // ---- CSR slot fill, dst-partitioned per XCD ----
    int part = blockIdx.x & 7;
    long long base = (long long)(blockIdx.x >> 3) * FS_CHUNK;
    int pl = (int)(((long long)n *  part     ) >> 3);
    int pr = (int)(((long long)n * (part + 1)) >> 3);
    bool i64 = (flag[1] > 0.5f);
    long long lim = base + FS_CHUNK < E ? base + FS_CHUNK : E;
    for (long long i = base + t; i < lim; i += 256){
      int s, d;
      if (i64){ s = ei[2*i]; d = ei[2*E + 2*i]; }
      else    { s = ei[i];   d = ei[E + i];     }
      if (d >= pl && d < pr && (unsigned)s < (unsigned)n){
        int p = atomicAdd(&cursor[d], 1);
        csr[p] = (IT)s;
      }
    }
    return;
  }
  // ---- MFMA layer 1 ----
  int bid = blockIdx.x - gF8;
  float isf = flag[0];
  for (int q = t; q < 384; q += 256){
    uint4 v = ((const uint4*)Wt1b)[q];
    *(uint4*)&Wt[q >> 2][(q & 3)*8] = v;
  }
  {
    int row = t >> 2, part = t & 3;
    int node = bid*64 + row;
    uint4 o;
    if (node < n){
      if (isf > 0.5f){
        const float* xr = (const float*)x + (size_t)32*node + 8*part;
        o.x = pk2(xr[0], xr[1]); o.y = pk2(xr[2], xr[3]);
        o.z = pk2(xr[4], xr[5]); o.w = pk2(xr[6], xr[7]);
      } else {
        o = ((const uint4*)x)[(size_t)4*node + part];
      }
    } else { o.x = o.y = o.z = o.w = 0u; }
    *(uint4*)&Xs[row][8*part] = o;
  }
  __syncthreads();

  int wv = t >> 6, lane = t & 63;
  int m = lane & 15, quad = lane >> 4;
  bf16x8 av = *(const bf16x8*)&Xs[16*wv + m][8*quad];
  f32x4 acc[6];
  #pragma unroll
  for (int c = 0; c < 6; ++c) acc[c] = (f32x4)(0.f);
  #pragma unroll
  for (int c = 0; c < 6; ++c){
    bf16x8 bv = *(const bf16x8*)&Wt[16*c + m][8*quad];
    acc[c] = __builtin_amdgcn_mfma_f32_16x16x32_bf16(av, bv, acc[c], 0, 0, 0);
  }
  int rowbase = bid*64 + 16*wv + 4*quad;
  float div[4];
  #pragma unroll
  for (int r = 0; r < 4; ++r){ int rr = rowbase + r; div[r] = (rr < n) ? dinv[rr] : 0.f; }
  #pragma unroll
  for (int c = 0; c < 6; ++c){
    int col = 16*c + m;
    #pragma unroll
    for (int r = 0; r < 4; ++r){
      int rr = rowbase + r;
      if (rr < n) HS[(size_t)96*rr + col] = f2bf(acc[c][r]*div[r]);
    }
  }
}

// ---------- CSR gather aggregation (bf16) + fused BN stats into 8-replica banks ----------
#define ACC8(v) { a0+=lo16((v).x); a1+=hi16((v).x); a2+=lo16((v).y); a3+=hi16((v).y); \
                  a4+=lo16((v).z); a5+=hi16((v).z); a6+=lo16((v).w); a7+=hi16((v).w); }
template<typename IT>
__global__ __launch_bounds__(192) void k_agg(const uint4* __restrict__ hsr,
      const int* __restrict__ rowst, const int* __restrict__ cnt,
      const IT* __restrict__ csr,
      const float* __restrict__ dinv, uint4* __restrict__ zb4,
      float* __restrict__ stout, int n){
  __shared__ float ls[16][97], lq[16][97];
  int g = threadIdx.x, ty = threadIdx.y;
  int t = ty*12 + g;
  int node = blockIdx.x*16 + ty;
  float r[8];
  if (node < n){
    uint4 v = hsr[(size_t)node*12 + g];            // self-loop term
    float a0 = lo16(v.x), a1 = hi16(v.x), a2 = lo16(v.y), a3 = hi16(v.y);
    float a4 = lo16(v.z), a5 = hi16(v.z), a6 = lo16(v.w), a7 = hi16(v.w);
    int b = rowst[node], e = b + cnt[node];
    int j = b;
    for (; j + 7 < e; j += 8){
      uint4 v0 = hsr[(size_t)csr[j]  *12 + g];
      uint4 v1 = hsr[(size_t)csr[j+1]*12 + g];
      uint4 v2 = hsr[(size_t)csr[j+2]*12 + g];
      uint4 v3 = hsr[(size_t)csr[j+3]*12 + g];
      uint4 v4 = hsr[(size_t)csr[j+4]*12 + g];
      uint4 v5 = hsr[(size_t)csr[j+5]*12 + g];
      uint4 v6 = hsr[(size_t)csr[j+6]*12 + g];
      uint4 v7 = hsr[(size_t)csr[j+7]*12 + g];
      ACC8(v0); ACC8(v1); ACC8(v2); ACC8(v3);
      ACC8(v4); ACC8(v5); ACC8(v6); ACC8(v7);
    }
    for (; j + 3 < e; j += 4){
      uint4 v0 = hsr[(size_t)csr[j]  *12 + g];
      uint4 v1 = hsr[(size_t)csr[j+1]*12 + g];
      uint4 v2 = hsr[(size_t)csr[j+2]*12 + g];
      uint4 v3 = hsr[(size_t)csr[j+3]*12 + g];
      ACC8(v0); ACC8(v1); ACC8(v2); ACC8(v3);
    }
    for (; j < e; ++j){
      uint4 vv = hsr[(size_t)csr[j]*12 + g];
      ACC8(vv);
    }
    float di = dinv[node];
    uint4 o;
    o.x = pk2(a0*di, a1*di);
    o.y = pk2(a2*di, a3*di);
    o.z = pk2(a4*di, a5*di);
    o.w = pk2(a6*di, a7*di);
    zb4[(size_t)node*12 + g] = o;
    r[0]=lo16(o.x); r[1]=hi16(o.x); r[2]=lo16(o.y); r[3]=hi16(o.y);
    r[4]=lo16(o.z); r[5]=hi16(o.z); r[6]=lo16(o.w); r[7]=hi16(o.w);
  } else {
    #pragma unroll
    for (int jj = 0; jj < 8; ++jj) r[jj] = 0.f;
  }
  #pragma unroll
  for (int jj = 0; jj < 8; ++jj){
    ls[ty][8*g + jj] = r[jj];
    lq[ty][8*g + jj] = r[jj]*r[jj];
  }
  __syncthreads();
  if (t < 96){
    float s = 0.f, q = 0.f;
    #pragma unroll
    for (int rr = 0; rr < 16; ++rr){ s += ls[rr][t]; q += lq[rr][t]; }
    int rep = blockIdx.x & 7;
    atomicAdd(&stout[192*rep + t],      s);
    atomicAdd(&stout[192*rep + 96 + t], q);
  }
}

// ---------- MFMA mid layer: HS = dinv * (relu(BN(Zb)) @ W); st = 8-replica sums ----------
__global__ __launch_bounds__(256) void k_linm(const unsigned short* __restrict__ zb,
      const unsigned short* __restrict__ Wtb, const float* __restrict__ st,
      const void* __restrict__ gam, const void* __restrict__ bet,
      const float* __restrict__ flag, const float* __restrict__ dinv,
      unsigned short* __restrict__ HS, int n, float invN){
  __shared__ float sa[96], sc[96];
  __shared__ __align__(16) unsigned short Ys[64][104];
  __shared__ __align__(16) unsigned short Wt[96][104];
  int t = threadIdx.x;
  if (t < 96){
    float ssum = 0.f, qsum = 0.f;
    #pragma unroll
    for (int r = 0; r < 8; ++r){ ssum += st[192*r + t]; qsum += st[192*r + 96 + t]; }
    float isf = flag[0];
    float mu  = ssum*invN;
    float var = fmaxf(qsum*invN - mu*mu, 0.f);
    float istd = rsqrtf(var + 1e-5f);
    float a = ldf(gam, t, isf)*istd;
    sa[t] = a; sc[t] = ldf(bet, t, isf) - mu*a;
  }
  for (int q = t; q < 1152; q += 256){
    uint4 v = ((const uint4*)Wtb)[q];
    *(uint4*)&Wt[q/12][8*(q - 12*(q/12))] = v;
  }
  __syncthreads();
  {
    int row = t >> 2, part = t & 3;
    int node = blockIdx.x*64 + row;
    if (node < n){
      const uint4* zr = (const uint4*)(zb + (size_t)96*node) + 3*part;
      #pragma unroll
      for (int q = 0; q < 3; ++q){
        uint4 zz = zr[q];
        int k = 24*part + 8*q;
        float y0 = fmaxf(lo16(zz.x)*sa[k]   + sc[k],   0.f);
        float y1 = fmaxf(hi16(zz.x)*sa[k+1] + sc[k+1], 0.f);
        float y2 = fmaxf(lo16(zz.y)*sa[k+2] + sc[k+2], 0.f);
        float y3 = fmaxf(hi16(zz.y)*sa[k+3] + sc[k+3], 0.f);
        float y4 = fmaxf(lo16(zz.z)*sa[k+4] + sc[k+4], 0.f);
        float y5 = fmaxf(hi16(zz.z)*sa[k+5] + sc[k+5], 0.f);
        float y6 = fmaxf(lo16(zz.w)*sa[k+6] + sc[k+6], 0.f);
        float y7 = fmaxf(hi16(zz.w)*sa[k+7] + sc[k+7], 0.f);
        *(unsigned int*)&Ys[row][k]     = pk2(y0, y1);
        *(unsigned int*)&Ys[row][k + 2] = pk2(y2, y3);
        *(unsigned int*)&Ys[row][k + 4] = pk2(y4, y5);
        *(unsigned int*)&Ys[row][k + 6] = pk2(y6, y7);
      }
    } else {
      unsigned int* yp = (unsigned int*)&Ys[row][24*part];
      #pragma unroll
      for (int q = 0; q < 12; ++q) yp[q] = 0u;
    }
  }
  __syncthreads();

  int wv = t >> 6, lane = t & 63;
  int m = lane & 15, quad = lane >> 4;
  bf16x8 av[3];
  #pragma unroll
  for (int kt = 0; kt < 3; ++kt)
    av[kt] = *(const bf16x8*)&Ys[16*wv + m][32*kt + 8*quad];
  f32x4 acc[6];
  #pragma unroll
  for (int c = 0; c < 6; ++c) acc[c] = (f32x4)(0.f);
  #pragma unroll
  for (int c = 0; c < 6; ++c){
    const unsigned short* wrow = &Wt[16*c + m][8*quad];
    #pragma unroll
    for (int kt = 0; kt < 3; ++kt){
      bf16x8 bv = *(const bf16x8*)(wrow + 32*kt);
      acc[c] = __builtin_amdgcn_mfma_f32_16x16x32_bf16(av[kt], bv, acc[c], 0, 0, 0);
    }
  }
  int rowbase = blockIdx.x*64 + 16*wv + 4*quad;
  float div[4];
  #pragma unroll
  for (int r = 0; r < 4; ++r){ int rr = rowbase + r; div[r] = (rr < n) ? dinv[rr] : 0.f; }
  #pragma unroll
  for (int c = 0; c < 6; ++c){
    int col = 16*c + m;
    #pragma unroll
    for (int r = 0; r < 4; ++r){
      int rr = rowbase + r;
      if (rr < n) HS[(size_t)96*rr + col] = f2bf(acc[c][r]*div[r]);
    }
  }
}

// ---------- layer 4 (96->2, VALU); st = 8-replica sums ----------
__global__ __launch_bounds__(256) void k_lin4(const unsigned short* __restrict__ zb,
      const float* __restrict__ Wf, const float* __restrict__ st,
      const void* __restrict__ gam, const void* __restrict__ bet,
      const float* __restrict__ flag, const float* __restrict__ dinv,
      float* __restrict__ hs2, int n, float invN){
  __shared__ float sa[96], sc[96];
  int t = threadIdx.x;
  if (t < 96){
    float ssum = 0.f, qsum = 0.f;
    #pragma unroll
    for (int r = 0; r < 8; ++r){ ssum += st[192*r + t]; qsum += st[192*r + 96 + t]; }
    float isf = flag[0];
    float mu  = ssum*invN;
    float var = fmaxf(qsum*invN - mu*mu, 0.f);
    float istd = rsqrtf(var + 1e-5f);
    float a = ldf(gam, t, isf)*istd;
    sa[t] = a; sc[t] = ldf(bet, t, isf) - mu*a;
  }
  __syncthreads();
  int i = blockIdx.x*blockDim.x + t;
  if (i >= n) return;
  const uint4* zr = (const uint4*)(zb + (size_t)96*i);
  float a0 = 0.f, a1 = 0.f;
  #pragma unroll
  for (int q = 0; q < 12; ++q){
    uint4 zz = zr[q];
    int k = 8*q;
    float y;
    y = fmaxf(lo16(zz.x)*sa[k]   + sc[k],   0.f); a0 += y*Wf[2*k];    a1 += y*Wf[2*k+1];
    y = fmaxf(hi16(zz.x)*sa[k+1] + sc[k+1], 0.f); a0 += y*Wf[2*k+2];  a1 += y*Wf[2*k+3];
    y = fmaxf(lo16(zz.y)*sa[k+2] + sc[k+2], 0.f); a0 += y*Wf[2*k+4];  a1 += y*Wf[2*k+5];
    y = fmaxf(hi16(zz.y)*sa[k+3] + sc[k+3], 0.f); a0 += y*Wf[2*k+6];  a1 += y*Wf[2*k+7];
    y = fmaxf(lo16(zz.z)*sa[k+4] + sc[k+4], 0.f); a0 += y*Wf[2*k+8];  a1 += y*Wf[2*k+9];
    y = fmaxf(hi16(zz.z)*sa[k+5] + sc[k+5], 0.f); a0 += y*Wf[2*k+10]; a1 += y*Wf[2*k+11];
    y = fmaxf(lo16(zz.w)*sa[k+6] + sc[k+6], 0.f); a0 += y*Wf[2*k+12]; a1 += y*Wf[2*k+13];
    y = fmaxf(hi16(zz.w)*sa[k+7] + sc[k+7], 0.f); a0 += y*Wf[2*k+14]; a1 += y*Wf[2*k+15];
  }
  float di = dinv[i];
  hs2[(size_t)2*i]   = di*a0;
  hs2[(size_t)2*i+1] = di*a1;
}

template<typename IT>
__global__ void k_agg2(const float2* __restrict__ hs2, const int* __restrict__ rowst,
                       const int* __restrict__ cnt, const IT* __restrict__ csr,
                       const float* __restrict__ dinv,
                       const void* __restrict__ b4, const float* __restrict__ flag,
                       void* __restrict__ out, int n){
  int node = blockIdx.x*blockDim.x + threadIdx.x;
  if (node >= n) return;
  float2 a = hs2[node];
  int b = rowst[node], e = b + cnt[node];
  for (int j = b; j < e; ++j){
    float2 v = hs2[(size_t)csr[j]];
    a.x += v.x; a.y += v.y;
  }
  float isf = flag[0];
  float di = dinv[node];
  float v0 = a.x*di + ldf(b4, 0, isf);
  float v1 = a.y*di + ldf(b4, 1, isf);
  if (isf > 0.5f){
    ((float*)out)[(size_t)2*node]   = v0;
    ((float*)out)[(size_t)2*node+1] = v1;
  } else {
    ((unsigned short*)out)[(size_t)2*node]   = f2bf(v0);
    ((unsigned short*)out)[(size_t)2*node+1] = f2bf(v1);
  }
}

extern "C" void kernel_launch(void* const* d_in, const int* in_sizes, int n_in,
                              void* d_out, int out_size, void* d_ws, size_t ws_size,
                              hipStream_t stream)
{
  const int B = 256;
  unsigned short* outh = (unsigned short*)d_out;

  if (n_in < 16){
    k_fill<<<(out_size+B-1)/B, B, 0, stream>>>(outh, 0x3F40u, out_size); return;
  }
  const int N = in_sizes[0] / 32;
  const long long E = in_sizes[1] / 2;
  if (in_sizes[0] % 32 != 0 || out_size != 2*N){
    k_fill<<<(out_size+B-1)/B, B, 0, stream>>>(outh, 0x3F60u, out_size); return;
  }
  const bool u16 = (N < 65536);

  // ---- workspace layout ----
  size_t Npad = ((size_t)N + 3) & ~(size_t)3;
  float* ws   = (float*)d_ws;
  float* dinv = ws;                               // Npad
  float* hs2  = dinv + Npad;                      // 2N
  float* flag = hs2 + (size_t)2*N;                // 4
  float* stAll= flag + 4;                         // 4608 stats + 1 gctr (+3 pad)
  float* W4f  = stAll + 4612;                     // 192
  unsigned short* Wt1b = (unsigned short*)(W4f + 192);   // 3072 bf16
  unsigned short* Wt2b = Wt1b + 3072;             // 9216
  unsigned short* Wt3b = Wt2b + 9216;             // 9216
  int* cnt    = (int*)(Wt3b + 9216);              // N
  int* cursor = cnt + N;                          // N
  int* rowst  = cursor + N;                       // N
  void* csrv  = (void*)(rowst + N);               // E entries (u16 or int)
  size_t csrBytes = (size_t)E * (u16 ? 2 : 4);
  uintptr_t hp_ = (uintptr_t)csrv + csrBytes;
  hp_ = (hp_ + 15) & ~(uintptr_t)15;
  unsigned short* HS = (unsigned short*)hp_;      // 96N bf16
  unsigned short* Zb = HS + (size_t)96*N;         // 96N bf16

  size_t needB = ((uintptr_t)(Zb + (size_t)96*N) - (uintptr_t)d_ws) + 64;
  if (ws_size < needB){
    k_fill<<<(out_size+B-1)/B, B, 0, stream>>>(outh, 0x3F00u, out_size); return;
  }

  const void* x  = d_in[0];
  const int*  ei = (const int*)d_in[1];
  const void* W1 = d_in[2];
  const void* g1 = d_in[4];  const void* be1 = d_in[5];
  const void* W2 = d_in[6];
  const void* g2 = d_in[8];  const void* be2 = d_in[9];
  const void* W3 = d_in[10];
  const void* g3 = d_in[12]; const void* be3 = d_in[13];
  const void* W4 = d_in[14];
  const void* b4 = d_in[15];

  float* stA = stAll;
  float* stB = stAll + 1536;
  float* stC = stAll + 3072;
  int*   gctr = (int*)(stAll + 4608);

  int gN  = (N + B - 1)/B;
  int gE  = (int)((E + B - 1)/B);
  int nb  = (N + 255)/256;
  int gA  = (N + 15)/16;
  int gL  = (N + 63)/64;
  int gF8 = (int)((E + FS_CHUNK - 1)/FS_CHUNK) * 8;
  float invN = 1.0f / (float)N;
  dim3 ablk(12,16);

  // 1) detect + weights + zero cnt/st/gctr
  k_prep<<<33, B, 0, stream>>>((const unsigned short*)x, (const unsigned int*)ei,
                               flag, in_sizes[0], E, W1, W2, W3, W4,
                               Wt1b, Wt2b, Wt3b, W4f, cnt, stAll, N);
  // 2) degree count
  k_cnt<<<gE, B, 0, stream>>>(ei, flag, cnt, E, N);
  // 3) unordered row allocation -> rowst, cursor, dinv
  k_emit2<<<nb, B, 0, stream>>>(cnt, gctr, rowst, cursor, dinv, N);

  if (u16){
    unsigned short* csr = (unsigned short*)csrv;
    // 4) CSR fill + MFMA layer 1 (merged, overlap)
    k_fl1<unsigned short><<<gF8 + gL, B, 0, stream>>>(ei, flag, cursor, csr, E, N, gF8,
                                                      x, Wt1b, dinv, HS);
    // 5..9) layers 1..3 agg(+stats) / linm
    k_agg<unsigned short><<<gA, ablk, 0, stream>>>((const uint4*)HS, rowst, cnt, csr, dinv, (uint4*)Zb, stA, N);
    k_linm<<<gL, B, 0, stream>>>(Zb, Wt2b, stA, g1, be1, flag, dinv, HS, N, invN);
    k_agg<unsigned short><<<gA, ablk, 0, stream>>>((const uint4*)HS, rowst, cnt, csr, dinv, (uint4*)Zb, stB, N);
    k_linm<<<gL, B, 0, stream>>>(Zb, Wt3b, stB, g2, be2, flag, dinv, HS, N, invN);
    k_agg<unsigned short><<<gA, ablk, 0, stream>>>((const uint4*)HS, rowst, cnt, csr, dinv, (uint4*)Zb, stC, N);
    // 10..11) layer 4 + output
    k_lin4<<<gN, B, 0, stream>>>(Zb, W4f, stC, g3, be3, flag, dinv, hs2, N, invN);
    k_agg2<unsigned short><<<gN, B, 0, stream>>>((const float2*)hs2, rowst, cnt, csr, dinv, b4, flag, d_out, N);
  } else {
    int* csr = (int*)csrv;
    k_fl1<int><<<gF8 + gL, B, 0, stream>>>(ei, flag, cursor, csr, E, N, gF8,
                                           x, Wt1b, dinv, HS);
    k_agg<int><<<gA, ablk, 0, stream>>>((const uint4*)HS, rowst, cnt, csr, dinv, (uint4*)Zb, stA, N);
    k_linm<<<gL, B, 0, stream>>>(Zb, Wt2b, stA, g1, be1, flag, dinv, HS, N, invN);
    k_agg<int><<<gA, ablk, 0, stream>>>((const uint4*)HS, rowst, cnt, csr, dinv, (uint4*)Zb, stB, N);
    k_linm<<<gL, B, 0, stream>>>(Zb, Wt3b, stB, g2, be2, flag, dinv, HS, N, invN);
    k_agg<int><<<gA, ablk, 0, stream>>>((const uint4*)HS, rowst, cnt, csr, dinv, (uint4*)Zb, stC, N);
    k_lin4<<<gN, B, 0, stream>>>(Zb, W4f, stC, g3, be3, flag, dinv, hs2, N, invN);
    k_agg2<int><<<gN, B, 0, stream>>>((const float2*)hs2, rowst, cnt, csr, dinv, b4, flag, d_out, N);
  }
}